// Round 1
// baseline (1544.298 us; speedup 1.0000x reference)
//
#include <hip/hip_runtime.h>

#define NN 10000     // nodes
#define NE 640000    // edges
#define D  128
#define H  256       // 2*D hidden
#define BN_EPS 1e-5f

// ---- workspace layout (float offsets) ----
#define OFF_SUMMED 0
#define OFF_DEG    (NN * D)                    // 1,280,000
#define OFF_STATS1 (OFF_DEG + NN)              // 1,290,000
#define OFF_STATS2 (OFF_STATS1 + 2 * H)        // 1,290,512
#define OFF_X1     (OFF_STATS2 + 2 * D)        // 1,290,768  (zeroed region ends here)
#define OFF_X2     (OFF_X1 + (size_t)NN * H)   // 3,850,768
#define OFF_NORM1  (OFF_X2 + (size_t)NN * D)   // 5,130,768
#define OFF_NORM2  (OFF_NORM1 + 2 * H)         // 5,131,280

// ---------------------------------------------------------------------------
// 1) message + scatter-add:  summed[dst] += node[src] + edge ;  deg[dst] += 1
//    32 threads per edge, float4 per thread.
// ---------------------------------------------------------------------------
__global__ __launch_bounds__(256) void scatter_kernel(
    const float* __restrict__ node, const float* __restrict__ edge,
    const int* __restrict__ src, const int* __restrict__ dst,
    float* __restrict__ summed, float* __restrict__ deg) {
  int idx = blockIdx.x * blockDim.x + threadIdx.x;
  const int total = NE * 32;
  if (idx >= total) return;
  int e = idx >> 5;
  int f = (idx & 31) << 2;
  int s = src[e];
  int d = dst[e];
  const float4 ef = *(const float4*)(edge + (size_t)e * D + f);
  const float4 nf = *(const float4*)(node + (size_t)s * D + f);
  float* o = summed + (size_t)d * D + f;
  atomicAdd(o + 0, ef.x + nf.x);
  atomicAdd(o + 1, ef.y + nf.y);
  atomicAdd(o + 2, ef.z + nf.z);
  atomicAdd(o + 3, ef.w + nf.w);
  if (f == 0) atomicAdd(deg + d, 1.0f);
}

// ---------------------------------------------------------------------------
// Tiled f32 GEMMs. TM=64, TN=64, TK=32, 256 threads, 4x4 micro-tile each.
// LDS leading dims padded to 68 (keeps 16B alignment; residual 2-way bank
// aliasing is free on gfx950).
// ---------------------------------------------------------------------------
#define TM 64
#define TN 64
#define TK 32
#define LDP 68

// GEMM1:  A[r][k] = (1+eps)*node[r][k] + summed[r][k]/max(deg[r],1)   (K=D)
//         X1 = A @ W1 + b1     (X1: [NN, H])
__global__ __launch_bounds__(256) void gemm1_kernel(
    const float* __restrict__ node, const float* __restrict__ summed,
    const float* __restrict__ deg, const float* __restrict__ epsp,
    const float* __restrict__ W1, const float* __restrict__ b1,
    float* __restrict__ X1) {
  __shared__ float As[TK][LDP];  // As[k][r]
  __shared__ float Bs[TK][LDP];  // Bs[k][c]
  const int tid = threadIdx.x;
  const int r0 = blockIdx.x * TM;
  const int c0 = blockIdx.y * TN;
  const int tx = tid & 15, ty = tid >> 4;
  const float one_eps = 1.0f + epsp[0];
  float acc[4][4] = {};

  for (int k0 = 0; k0 < D; k0 += TK) {
#pragma unroll
    for (int l = 0; l < 2; ++l) {
      int e = tid + l * 256;      // 0..511
      int kg = e & 7;             // float4 group along k
      int r = e >> 3;             // 0..63
      int row = r0 + r;
      int rc = row < NN ? row : NN - 1;
      float rd = deg[rc];
      rd = 1.0f / fmaxf(rd, 1.0f);
      const float4 nf = *(const float4*)(node + (size_t)rc * D + k0 + kg * 4);
      const float4 sm = *(const float4*)(summed + (size_t)rc * D + k0 + kg * 4);
      As[kg * 4 + 0][r] = one_eps * nf.x + sm.x * rd;
      As[kg * 4 + 1][r] = one_eps * nf.y + sm.y * rd;
      As[kg * 4 + 2][r] = one_eps * nf.z + sm.z * rd;
      As[kg * 4 + 3][r] = one_eps * nf.w + sm.w * rd;
    }
#pragma unroll
    for (int l = 0; l < 2; ++l) {
      int e = tid + l * 256;
      int cg = e & 15;            // float4 group along c (16 per 64 cols)
      int k = e >> 4;             // 0..31
      *(float4*)&Bs[k][cg * 4] =
          *(const float4*)(W1 + (size_t)(k0 + k) * H + c0 + cg * 4);
    }
    __syncthreads();
#pragma unroll
    for (int kk = 0; kk < TK; ++kk) {
      float4 av = *(const float4*)&As[kk][ty * 4];
      float4 bv = *(const float4*)&Bs[kk][tx * 4];
      float a[4] = {av.x, av.y, av.z, av.w};
      float b[4] = {bv.x, bv.y, bv.z, bv.w};
#pragma unroll
      for (int i = 0; i < 4; ++i)
#pragma unroll
        for (int j = 0; j < 4; ++j) acc[i][j] += a[i] * b[j];
    }
    __syncthreads();
  }
  float4 bias = *(const float4*)(b1 + c0 + tx * 4);
#pragma unroll
  for (int i = 0; i < 4; ++i) {
    int row = r0 + ty * 4 + i;
    if (row < NN) {
      float4 o;
      o.x = acc[i][0] + bias.x;
      o.y = acc[i][1] + bias.y;
      o.z = acc[i][2] + bias.z;
      o.w = acc[i][3] + bias.w;
      *(float4*)(X1 + (size_t)row * H + c0 + tx * 4) = o;
    }
  }
}

// GEMM2:  A[r][k] = relu(X1[r][k]*scale1[k] + shift1[k])   (K=H)
//         X2 = A @ W2 + b2     (X2: [NN, D])
__global__ __launch_bounds__(256) void gemm2_kernel(
    const float* __restrict__ X1, const float* __restrict__ norm1,
    const float* __restrict__ W2, const float* __restrict__ b2,
    float* __restrict__ X2) {
  __shared__ float As[TK][LDP];
  __shared__ float Bs[TK][LDP];
  const int tid = threadIdx.x;
  const int r0 = blockIdx.x * TM;
  const int c0 = blockIdx.y * TN;
  const int tx = tid & 15, ty = tid >> 4;
  float acc[4][4] = {};

  for (int k0 = 0; k0 < H; k0 += TK) {
#pragma unroll
    for (int l = 0; l < 2; ++l) {
      int e = tid + l * 256;
      int kg = e & 7;
      int r = e >> 3;
      int row = r0 + r;
      int rc = row < NN ? row : NN - 1;
      const float4 xv = *(const float4*)(X1 + (size_t)rc * H + k0 + kg * 4);
      const float4 sc = *(const float4*)(norm1 + k0 + kg * 4);
      const float4 sh = *(const float4*)(norm1 + H + k0 + kg * 4);
      As[kg * 4 + 0][r] = fmaxf(xv.x * sc.x + sh.x, 0.0f);
      As[kg * 4 + 1][r] = fmaxf(xv.y * sc.y + sh.y, 0.0f);
      As[kg * 4 + 2][r] = fmaxf(xv.z * sc.z + sh.z, 0.0f);
      As[kg * 4 + 3][r] = fmaxf(xv.w * sc.w + sh.w, 0.0f);
    }
#pragma unroll
    for (int l = 0; l < 2; ++l) {
      int e = tid + l * 256;
      int cg = e & 15;
      int k = e >> 4;
      *(float4*)&Bs[k][cg * 4] =
          *(const float4*)(W2 + (size_t)(k0 + k) * D + c0 + cg * 4);
    }
    __syncthreads();
#pragma unroll
    for (int kk = 0; kk < TK; ++kk) {
      float4 av = *(const float4*)&As[kk][ty * 4];
      float4 bv = *(const float4*)&Bs[kk][tx * 4];
      float a[4] = {av.x, av.y, av.z, av.w};
      float b[4] = {bv.x, bv.y, bv.z, bv.w};
#pragma unroll
      for (int i = 0; i < 4; ++i)
#pragma unroll
        for (int j = 0; j < 4; ++j) acc[i][j] += a[i] * b[j];
    }
    __syncthreads();
  }
  float4 bias = *(const float4*)(b2 + c0 + tx * 4);
#pragma unroll
  for (int i = 0; i < 4; ++i) {
    int row = r0 + ty * 4 + i;
    if (row < NN) {
      float4 o;
      o.x = acc[i][0] + bias.x;
      o.y = acc[i][1] + bias.y;
      o.z = acc[i][2] + bias.z;
      o.w = acc[i][3] + bias.w;
      *(float4*)(X2 + (size_t)row * D + c0 + tx * 4) = o;
    }
  }
}

// ---------------------------------------------------------------------------
// Column sum / sum-of-squares over NN rows (for BatchNorm batch stats).
// Thread t handles column t%C; consecutive threads -> consecutive columns
// (coalesced row-major reads).
// ---------------------------------------------------------------------------
template <int C>
__global__ __launch_bounds__(256) void colstats_kernel(
    const float* __restrict__ X, float* __restrict__ stats) {
  const int t = threadIdx.x;
  const int RPB = 256 / C;
  const int col = t % C;
  int r = blockIdx.x * RPB + t / C;
  const int stride = gridDim.x * RPB;
  float s = 0.0f, q = 0.0f;
  for (; r < NN; r += stride) {
    float v = X[(size_t)r * C + col];
    s += v;
    q += v * v;
  }
  atomicAdd(&stats[col], s);
  atomicAdd(&stats[C + col], q);
}

template <int C>
__global__ void finalize_norm_kernel(const float* __restrict__ stats,
                                     const float* __restrict__ gamma,
                                     const float* __restrict__ beta,
                                     float* __restrict__ norm) {
  int t = threadIdx.x;
  if (t < C) {
    const float inv_n = 1.0f / (float)NN;
    float mu = stats[t] * inv_n;
    float var = stats[C + t] * inv_n - mu * mu;
    float sc = gamma[t] * rsqrtf(var + BN_EPS);
    norm[t] = sc;
    norm[C + t] = beta[t] - mu * sc;
  }
}

// out = relu(X2 * scale2[c] + shift2[c])
__global__ __launch_bounds__(256) void final_kernel(
    const float* __restrict__ X2, const float* __restrict__ norm2,
    float* __restrict__ out) {
  int idx = blockIdx.x * blockDim.x + threadIdx.x;
  if (idx >= NN * D / 4) return;
  int c4 = (idx & (D / 4 - 1)) * 4;
  float4 v = *(const float4*)(X2 + (size_t)idx * 4);
  float4 sc = *(const float4*)(norm2 + c4);
  float4 sh = *(const float4*)(norm2 + D + c4);
  float4 o;
  o.x = fmaxf(v.x * sc.x + sh.x, 0.0f);
  o.y = fmaxf(v.y * sc.y + sh.y, 0.0f);
  o.z = fmaxf(v.z * sc.z + sh.z, 0.0f);
  o.w = fmaxf(v.w * sc.w + sh.w, 0.0f);
  *(float4*)(out + (size_t)idx * 4) = o;
}

extern "C" void kernel_launch(void* const* d_in, const int* in_sizes, int n_in,
                              void* d_out, int out_size, void* d_ws,
                              size_t ws_size, hipStream_t stream) {
  const float* node = (const float*)d_in[0];
  const float* edge = (const float*)d_in[1];
  const float* eps = (const float*)d_in[2];
  const float* W1 = (const float*)d_in[3];
  const float* b1 = (const float*)d_in[4];
  const float* g1 = (const float*)d_in[5];
  const float* be1 = (const float*)d_in[6];
  const float* W2 = (const float*)d_in[7];
  const float* b2 = (const float*)d_in[8];
  const float* g2 = (const float*)d_in[9];
  const float* be2 = (const float*)d_in[10];
  const int* src = (const int*)d_in[11];
  const int* dst = (const int*)d_in[12];
  float* ws = (float*)d_ws;
  float* out = (float*)d_out;

  // zero: summed, deg, stats1, stats2
  hipMemsetAsync(ws, 0, (size_t)OFF_X1 * sizeof(float), stream);

  scatter_kernel<<<(NE * 32 + 255) / 256, 256, 0, stream>>>(
      node, edge, src, dst, ws + OFF_SUMMED, ws + OFF_DEG);

  dim3 grid1((NN + TM - 1) / TM, H / TN);
  gemm1_kernel<<<grid1, 256, 0, stream>>>(node, ws + OFF_SUMMED, ws + OFF_DEG,
                                          eps, W1, b1, ws + OFF_X1);

  colstats_kernel<H><<<512, 256, 0, stream>>>(ws + OFF_X1, ws + OFF_STATS1);
  finalize_norm_kernel<H><<<1, H, 0, stream>>>(ws + OFF_STATS1, g1, be1,
                                               ws + OFF_NORM1);

  dim3 grid2((NN + TM - 1) / TM, D / TN);
  gemm2_kernel<<<grid2, 256, 0, stream>>>(ws + OFF_X1, ws + OFF_NORM1, W2, b2,
                                          ws + OFF_X2);

  colstats_kernel<D><<<512, 256, 0, stream>>>(ws + OFF_X2, ws + OFF_STATS2);
  finalize_norm_kernel<D><<<1, D, 0, stream>>>(ws + OFF_STATS2, g2, be2,
                                               ws + OFF_NORM2);

  final_kernel<<<(NN * D / 4 + 255) / 256, 256, 0, stream>>>(
      ws + OFF_X2, ws + OFF_NORM2, out);
}

// Round 2
// 698.706 us; speedup vs baseline: 2.2102x; 2.2102x over previous
//
#include <hip/hip_runtime.h>

#define NN 10000     // nodes
#define NE 640000    // edges
#define D  128
#define H  256       // 2*D hidden
#define BN_EPS 1e-5f

// ---- workspace layout (4-byte element offsets) ----
#define OFF_CNT    0                           // NN ints (zeroed)
#define OFF_STATS1 (NN)                        // 2H floats (zeroed)
#define OFF_STATS2 (NN + 2 * H)                // 2D floats (zeroed)
#define ZERO_ELEMS (NN + 2 * H + 2 * D)        // 10768
#define OFF_RS     ZERO_ELEMS                  // NN+1 ints
#define OFF_CUR    (OFF_RS + NN + 4)           // NN ints (padded to %4==0)
#define OFF_EID    (OFF_CUR + NN)              // NE ints
#define OFF_A      (OFF_EID + NE)              // NN*D floats (670772, %4==0)
#define OFF_X1     (OFF_A + (size_t)NN * D)    // NN*H floats
#define OFF_X2     (OFF_X1 + (size_t)NN * H)   // NN*D floats
#define OFF_NORM1  (OFF_X2 + (size_t)NN * D)   // 2H floats
#define OFF_NORM2  (OFF_NORM1 + 2 * H)         // 2D floats

// ---------------------------------------------------------------------------
// CSR build: histogram -> exclusive scan -> fill edge-id buckets
// ---------------------------------------------------------------------------
__global__ __launch_bounds__(256) void hist_kernel(const int* __restrict__ dst,
                                                   int* __restrict__ cnt) {
  int e = blockIdx.x * blockDim.x + threadIdx.x;
  if (e < NE) atomicAdd(&cnt[dst[e]], 1);
}

// single block, 256 threads; each thread scans a 40-element chunk serially.
__global__ __launch_bounds__(256) void scan_kernel(const int* __restrict__ cnt,
                                                   int* __restrict__ rs,
                                                   int* __restrict__ cur) {
  __shared__ int part[256];
  __shared__ int tmp[256];
  const int t = threadIdx.x;
  const int CH = 40;  // 256*40 >= 10000
  int base = t * CH;
  int s = 0;
  for (int i = 0; i < CH; ++i) {
    int idx = base + i;
    if (idx < NN) s += cnt[idx];
  }
  part[t] = s;
  __syncthreads();
  // Hillis-Steele inclusive scan over 256 partials
  int v = part[t];
  for (int off = 1; off < 256; off <<= 1) {
    tmp[t] = v;
    __syncthreads();
    if (t >= off) v += tmp[t - off];
    __syncthreads();
  }
  int excl = v - part[t];  // exclusive prefix of this thread's chunk
  int run = excl;
  for (int i = 0; i < CH; ++i) {
    int idx = base + i;
    if (idx < NN) {
      rs[idx] = run;
      cur[idx] = run;
      run += cnt[idx];
    }
  }
  if (t == 0) rs[NN] = NE;
}

__global__ __launch_bounds__(256) void fill_kernel(const int* __restrict__ dst,
                                                   int* __restrict__ cur,
                                                   int* __restrict__ eid) {
  int e = blockIdx.x * blockDim.x + threadIdx.x;
  if (e < NE) {
    int pos = atomicAdd(&cur[dst[e]], 1);
    eid[pos] = e;
  }
}

// ---------------------------------------------------------------------------
// Gather: one 64-lane wave per destination node. lane covers float2 of the
// 128-wide feature row. A[d] = (1+eps)*node[d] + mean_e(node[src]+edge[e]).
// ---------------------------------------------------------------------------
__global__ __launch_bounds__(256) void gather_kernel(
    const float* __restrict__ node, const float* __restrict__ edge,
    const int* __restrict__ src, const int* __restrict__ rs,
    const int* __restrict__ eid, const float* __restrict__ epsp,
    float* __restrict__ A) {
  int wid = (blockIdx.x * 256 + (int)threadIdx.x) >> 6;
  int lane = threadIdx.x & 63;
  if (wid >= NN) return;
  const int beg = rs[wid];
  const int end = rs[wid + 1];
  const int fo = lane * 2;
  float ax = 0.0f, ay = 0.0f;
  int i = beg;
  for (; i + 1 < end; i += 2) {
    int e0 = eid[i], e1 = eid[i + 1];
    int s0 = src[e0], s1 = src[e1];
    float2 ev0 = *(const float2*)(edge + (size_t)e0 * D + fo);
    float2 nv0 = *(const float2*)(node + (size_t)s0 * D + fo);
    float2 ev1 = *(const float2*)(edge + (size_t)e1 * D + fo);
    float2 nv1 = *(const float2*)(node + (size_t)s1 * D + fo);
    ax += (ev0.x + nv0.x) + (ev1.x + nv1.x);
    ay += (ev0.y + nv0.y) + (ev1.y + nv1.y);
  }
  if (i < end) {
    int e0 = eid[i];
    int s0 = src[e0];
    float2 ev0 = *(const float2*)(edge + (size_t)e0 * D + fo);
    float2 nv0 = *(const float2*)(node + (size_t)s0 * D + fo);
    ax += ev0.x + nv0.x;
    ay += ev0.y + nv0.y;
  }
  const float rdeg = 1.0f / fmaxf((float)(end - beg), 1.0f);
  const float one_eps = 1.0f + epsp[0];
  float2 nself = *(const float2*)(node + (size_t)wid * D + fo);
  float2 o;
  o.x = one_eps * nself.x + ax * rdeg;
  o.y = one_eps * nself.y + ay * rdeg;
  *(float2*)(A + (size_t)wid * D + fo) = o;
}

// ---------------------------------------------------------------------------
// Tiled f32 GEMMs. TM=64, TN=64, TK=32, 256 threads, 4x4 micro-tile each.
// ---------------------------------------------------------------------------
#define TM 64
#define TN 64
#define TK 32
#define LDP 68

// GEMM1:  X1 = A @ W1 + b1     (A: [NN, D], X1: [NN, H])
__global__ __launch_bounds__(256) void gemm1_kernel(
    const float* __restrict__ A, const float* __restrict__ W1,
    const float* __restrict__ b1, float* __restrict__ X1) {
  __shared__ float As[TK][LDP];  // As[k][r]
  __shared__ float Bs[TK][LDP];  // Bs[k][c]
  const int tid = threadIdx.x;
  const int r0 = blockIdx.x * TM;
  const int c0 = blockIdx.y * TN;
  const int tx = tid & 15, ty = tid >> 4;
  float acc[4][4] = {};

  for (int k0 = 0; k0 < D; k0 += TK) {
#pragma unroll
    for (int l = 0; l < 2; ++l) {
      int e = tid + l * 256;      // 0..511
      int kg = e & 7;             // float4 group along k
      int r = e >> 3;             // 0..63
      int row = r0 + r;
      int rc = row < NN ? row : NN - 1;
      const float4 av = *(const float4*)(A + (size_t)rc * D + k0 + kg * 4);
      As[kg * 4 + 0][r] = av.x;
      As[kg * 4 + 1][r] = av.y;
      As[kg * 4 + 2][r] = av.z;
      As[kg * 4 + 3][r] = av.w;
    }
#pragma unroll
    for (int l = 0; l < 2; ++l) {
      int e = tid + l * 256;
      int cg = e & 15;            // float4 group along c
      int k = e >> 4;             // 0..31
      *(float4*)&Bs[k][cg * 4] =
          *(const float4*)(W1 + (size_t)(k0 + k) * H + c0 + cg * 4);
    }
    __syncthreads();
#pragma unroll
    for (int kk = 0; kk < TK; ++kk) {
      float4 av = *(const float4*)&As[kk][ty * 4];
      float4 bv = *(const float4*)&Bs[kk][tx * 4];
      float a[4] = {av.x, av.y, av.z, av.w};
      float b[4] = {bv.x, bv.y, bv.z, bv.w};
#pragma unroll
      for (int i = 0; i < 4; ++i)
#pragma unroll
        for (int j = 0; j < 4; ++j) acc[i][j] += a[i] * b[j];
    }
    __syncthreads();
  }
  float4 bias = *(const float4*)(b1 + c0 + tx * 4);
#pragma unroll
  for (int i = 0; i < 4; ++i) {
    int row = r0 + ty * 4 + i;
    if (row < NN) {
      float4 o;
      o.x = acc[i][0] + bias.x;
      o.y = acc[i][1] + bias.y;
      o.z = acc[i][2] + bias.z;
      o.w = acc[i][3] + bias.w;
      *(float4*)(X1 + (size_t)row * H + c0 + tx * 4) = o;
    }
  }
}

// GEMM2:  A[r][k] = relu(X1[r][k]*scale1[k] + shift1[k])   (K=H)
//         X2 = A @ W2 + b2     (X2: [NN, D])
__global__ __launch_bounds__(256) void gemm2_kernel(
    const float* __restrict__ X1, const float* __restrict__ norm1,
    const float* __restrict__ W2, const float* __restrict__ b2,
    float* __restrict__ X2) {
  __shared__ float As[TK][LDP];
  __shared__ float Bs[TK][LDP];
  const int tid = threadIdx.x;
  const int r0 = blockIdx.x * TM;
  const int c0 = blockIdx.y * TN;
  const int tx = tid & 15, ty = tid >> 4;
  float acc[4][4] = {};

  for (int k0 = 0; k0 < H; k0 += TK) {
#pragma unroll
    for (int l = 0; l < 2; ++l) {
      int e = tid + l * 256;
      int kg = e & 7;
      int r = e >> 3;
      int row = r0 + r;
      int rc = row < NN ? row : NN - 1;
      const float4 xv = *(const float4*)(X1 + (size_t)rc * H + k0 + kg * 4);
      const float4 sc = *(const float4*)(norm1 + k0 + kg * 4);
      const float4 sh = *(const float4*)(norm1 + H + k0 + kg * 4);
      As[kg * 4 + 0][r] = fmaxf(xv.x * sc.x + sh.x, 0.0f);
      As[kg * 4 + 1][r] = fmaxf(xv.y * sc.y + sh.y, 0.0f);
      As[kg * 4 + 2][r] = fmaxf(xv.z * sc.z + sh.z, 0.0f);
      As[kg * 4 + 3][r] = fmaxf(xv.w * sc.w + sh.w, 0.0f);
    }
#pragma unroll
    for (int l = 0; l < 2; ++l) {
      int e = tid + l * 256;
      int cg = e & 15;
      int k = e >> 4;
      *(float4*)&Bs[k][cg * 4] =
          *(const float4*)(W2 + (size_t)(k0 + k) * D + c0 + cg * 4);
    }
    __syncthreads();
#pragma unroll
    for (int kk = 0; kk < TK; ++kk) {
      float4 av = *(const float4*)&As[kk][ty * 4];
      float4 bv = *(const float4*)&Bs[kk][tx * 4];
      float a[4] = {av.x, av.y, av.z, av.w};
      float b[4] = {bv.x, bv.y, bv.z, bv.w};
#pragma unroll
      for (int i = 0; i < 4; ++i)
#pragma unroll
        for (int j = 0; j < 4; ++j) acc[i][j] += a[i] * b[j];
    }
    __syncthreads();
  }
  float4 bias = *(const float4*)(b2 + c0 + tx * 4);
#pragma unroll
  for (int i = 0; i < 4; ++i) {
    int row = r0 + ty * 4 + i;
    if (row < NN) {
      float4 o;
      o.x = acc[i][0] + bias.x;
      o.y = acc[i][1] + bias.y;
      o.z = acc[i][2] + bias.z;
      o.w = acc[i][3] + bias.w;
      *(float4*)(X2 + (size_t)row * D + c0 + tx * 4) = o;
    }
  }
}

// ---------------------------------------------------------------------------
// Column sum / sum-of-squares over NN rows (BatchNorm batch stats).
// ---------------------------------------------------------------------------
template <int C>
__global__ __launch_bounds__(256) void colstats_kernel(
    const float* __restrict__ X, float* __restrict__ stats) {
  const int t = threadIdx.x;
  const int RPB = 256 / C;
  const int col = t % C;
  int r = blockIdx.x * RPB + t / C;
  const int stride = gridDim.x * RPB;
  float s = 0.0f, q = 0.0f;
  for (; r < NN; r += stride) {
    float v = X[(size_t)r * C + col];
    s += v;
    q += v * v;
  }
  atomicAdd(&stats[col], s);
  atomicAdd(&stats[C + col], q);
}

template <int C>
__global__ void finalize_norm_kernel(const float* __restrict__ stats,
                                     const float* __restrict__ gamma,
                                     const float* __restrict__ beta,
                                     float* __restrict__ norm) {
  int t = threadIdx.x;
  if (t < C) {
    const float inv_n = 1.0f / (float)NN;
    float mu = stats[t] * inv_n;
    float var = stats[C + t] * inv_n - mu * mu;
    float sc = gamma[t] * rsqrtf(var + BN_EPS);
    norm[t] = sc;
    norm[C + t] = beta[t] - mu * sc;
  }
}

// out = relu(X2 * scale2[c] + shift2[c])
__global__ __launch_bounds__(256) void final_kernel(
    const float* __restrict__ X2, const float* __restrict__ norm2,
    float* __restrict__ out) {
  int idx = blockIdx.x * blockDim.x + threadIdx.x;
  if (idx >= NN * D / 4) return;
  int c4 = (idx & (D / 4 - 1)) * 4;
  float4 v = *(const float4*)(X2 + (size_t)idx * 4);
  float4 sc = *(const float4*)(norm2 + c4);
  float4 sh = *(const float4*)(norm2 + D + c4);
  float4 o;
  o.x = fmaxf(v.x * sc.x + sh.x, 0.0f);
  o.y = fmaxf(v.y * sc.y + sh.y, 0.0f);
  o.z = fmaxf(v.z * sc.z + sh.z, 0.0f);
  o.w = fmaxf(v.w * sc.w + sh.w, 0.0f);
  *(float4*)(out + (size_t)idx * 4) = o;
}

extern "C" void kernel_launch(void* const* d_in, const int* in_sizes, int n_in,
                              void* d_out, int out_size, void* d_ws,
                              size_t ws_size, hipStream_t stream) {
  const float* node = (const float*)d_in[0];
  const float* edge = (const float*)d_in[1];
  const float* eps = (const float*)d_in[2];
  const float* W1 = (const float*)d_in[3];
  const float* b1 = (const float*)d_in[4];
  const float* g1 = (const float*)d_in[5];
  const float* be1 = (const float*)d_in[6];
  const float* W2 = (const float*)d_in[7];
  const float* b2 = (const float*)d_in[8];
  const float* g2 = (const float*)d_in[9];
  const float* be2 = (const float*)d_in[10];
  const int* src = (const int*)d_in[11];
  const int* dst = (const int*)d_in[12];
  float* ws = (float*)d_ws;
  int* wsi = (int*)d_ws;
  float* out = (float*)d_out;

  // zero: cnt, stats1, stats2
  hipMemsetAsync(ws, 0, (size_t)ZERO_ELEMS * sizeof(float), stream);

  hist_kernel<<<(NE + 255) / 256, 256, 0, stream>>>(dst, wsi + OFF_CNT);
  scan_kernel<<<1, 256, 0, stream>>>(wsi + OFF_CNT, wsi + OFF_RS,
                                     wsi + OFF_CUR);
  fill_kernel<<<(NE + 255) / 256, 256, 0, stream>>>(dst, wsi + OFF_CUR,
                                                    wsi + OFF_EID);
  gather_kernel<<<(NN * 64 + 255) / 256, 256, 0, stream>>>(
      node, edge, src, wsi + OFF_RS, wsi + OFF_EID, eps, ws + OFF_A);

  dim3 grid1((NN + TM - 1) / TM, H / TN);
  gemm1_kernel<<<grid1, 256, 0, stream>>>(ws + OFF_A, W1, b1, ws + OFF_X1);

  colstats_kernel<H><<<512, 256, 0, stream>>>(ws + OFF_X1, ws + OFF_STATS1);
  finalize_norm_kernel<H><<<1, H, 0, stream>>>(ws + OFF_STATS1, g1, be1,
                                               ws + OFF_NORM1);

  dim3 grid2((NN + TM - 1) / TM, D / TN);
  gemm2_kernel<<<grid2, 256, 0, stream>>>(ws + OFF_X1, ws + OFF_NORM1, W2, b2,
                                          ws + OFF_X2);

  colstats_kernel<D><<<512, 256, 0, stream>>>(ws + OFF_X2, ws + OFF_STATS2);
  finalize_norm_kernel<D><<<1, D, 0, stream>>>(ws + OFF_STATS2, g2, be2,
                                               ws + OFF_NORM2);

  final_kernel<<<(NN * D / 4 + 255) / 256, 256, 0, stream>>>(
      ws + OFF_X2, ws + OFF_NORM2, out);
}

// Round 3
// 658.870 us; speedup vs baseline: 2.3439x; 1.0605x over previous
//
#include <hip/hip_runtime.h>

#define NN 10000     // nodes
#define NE 640000    // edges
#define D  128
#define H  256       // 2*D hidden
#define BN_EPS 1e-5f

// ---- workspace layout (4-byte element offsets) ----
#define OFF_CNT    0                           // NN ints (zeroed)
#define OFF_STATS1 (NN)                        // 2H floats (zeroed)
#define OFF_STATS2 (NN + 2 * H)                // 2D floats (zeroed)
#define ZERO_ELEMS (NN + 2 * H + 2 * D)        // 10768
#define OFF_RS     ZERO_ELEMS                  // NN+1 ints
#define OFF_CUR    (OFF_RS + NN + 4)           // NN ints (padded to %4==0)
#define OFF_EID    (OFF_CUR + NN)              // NE ints
#define OFF_A      (OFF_EID + NE)              // NN*D floats (670772, %4==0)
#define OFF_X1     (OFF_A + (size_t)NN * D)    // NN*H floats
#define OFF_X2     (OFF_X1 + (size_t)NN * H)   // NN*D floats
#define OFF_NORM1  (OFF_X2 + (size_t)NN * D)   // 2H floats
#define OFF_NORM2  (OFF_NORM1 + 2 * H)         // 2D floats

// ---------------------------------------------------------------------------
// CSR build: histogram -> exclusive scan -> fill edge-id buckets
// ---------------------------------------------------------------------------
__global__ __launch_bounds__(256) void hist_kernel(const int* __restrict__ dst,
                                                   int* __restrict__ cnt) {
  int e = blockIdx.x * blockDim.x + threadIdx.x;
  if (e < NE) atomicAdd(&cnt[dst[e]], 1);
}

// single block, 256 threads; each thread scans a 40-element chunk serially.
__global__ __launch_bounds__(256) void scan_kernel(const int* __restrict__ cnt,
                                                   int* __restrict__ rs,
                                                   int* __restrict__ cur) {
  __shared__ int part[256];
  __shared__ int tmp[256];
  const int t = threadIdx.x;
  const int CH = 40;  // 256*40 >= 10000
  int base = t * CH;
  int s = 0;
  for (int i = 0; i < CH; ++i) {
    int idx = base + i;
    if (idx < NN) s += cnt[idx];
  }
  part[t] = s;
  __syncthreads();
  // Hillis-Steele inclusive scan over 256 partials
  int v = part[t];
  for (int off = 1; off < 256; off <<= 1) {
    tmp[t] = v;
    __syncthreads();
    if (t >= off) v += tmp[t - off];
    __syncthreads();
  }
  int excl = v - part[t];  // exclusive prefix of this thread's chunk
  int run = excl;
  for (int i = 0; i < CH; ++i) {
    int idx = base + i;
    if (idx < NN) {
      rs[idx] = run;
      cur[idx] = run;
      run += cnt[idx];
    }
  }
  if (t == 0) rs[NN] = NE;
}

__global__ __launch_bounds__(256) void fill_kernel(const int* __restrict__ dst,
                                                   int* __restrict__ cur,
                                                   int* __restrict__ eid) {
  int e = blockIdx.x * blockDim.x + threadIdx.x;
  if (e < NE) {
    int pos = atomicAdd(&cur[dst[e]], 1);
    eid[pos] = e;
  }
}

// ---------------------------------------------------------------------------
// Gather v2: one 64-lane wave per destination node; each 32-lane HALF covers
// one full 512B feature row per float4 load (lane covers (lane&31)*4..+3).
// 4 edges per iteration, unroll 2 -> 8 edges of loads in flight.
// A[d] = (1+eps)*node[d] + mean_e(node[src]+edge[e]).
// ---------------------------------------------------------------------------
__global__ __launch_bounds__(256) void gather_kernel(
    const float* __restrict__ node, const float* __restrict__ edge,
    const int* __restrict__ src, const int* __restrict__ rs,
    const int* __restrict__ eid, const float* __restrict__ epsp,
    float* __restrict__ A) {
  int wid = (blockIdx.x * 256 + (int)threadIdx.x) >> 6;
  if (wid >= NN) return;
  const int lane = threadIdx.x & 63;
  const int half = lane >> 5;
  const int fo = (lane & 31) * 4;
  const int beg = rs[wid];
  const int end = rs[wid + 1];
  float4 acc = {0.0f, 0.0f, 0.0f, 0.0f};
  int i = beg;
#pragma unroll 2
  for (; i + 3 < end; i += 4) {
    int ea = eid[i + half];
    int eb = eid[i + 2 + half];
    int sa = src[ea];
    int sb = src[eb];
    float4 ev0 = *(const float4*)(edge + (size_t)ea * D + fo);
    float4 nv0 = *(const float4*)(node + (size_t)sa * D + fo);
    float4 ev1 = *(const float4*)(edge + (size_t)eb * D + fo);
    float4 nv1 = *(const float4*)(node + (size_t)sb * D + fo);
    acc.x += (ev0.x + nv0.x) + (ev1.x + nv1.x);
    acc.y += (ev0.y + nv0.y) + (ev1.y + nv1.y);
    acc.z += (ev0.z + nv0.z) + (ev1.z + nv1.z);
    acc.w += (ev0.w + nv0.w) + (ev1.w + nv1.w);
  }
  for (; i + 1 < end; i += 2) {
    int ea = eid[i + half];
    int sa = src[ea];
    float4 ev0 = *(const float4*)(edge + (size_t)ea * D + fo);
    float4 nv0 = *(const float4*)(node + (size_t)sa * D + fo);
    acc.x += ev0.x + nv0.x;
    acc.y += ev0.y + nv0.y;
    acc.z += ev0.z + nv0.z;
    acc.w += ev0.w + nv0.w;
  }
  if (i < end && half == 0) {
    int ea = eid[i];
    int sa = src[ea];
    float4 ev0 = *(const float4*)(edge + (size_t)ea * D + fo);
    float4 nv0 = *(const float4*)(node + (size_t)sa * D + fo);
    acc.x += ev0.x + nv0.x;
    acc.y += ev0.y + nv0.y;
    acc.z += ev0.z + nv0.z;
    acc.w += ev0.w + nv0.w;
  }
  // combine the two halves (each half holds a full partial of the same cols)
  acc.x += __shfl_xor(acc.x, 32, 64);
  acc.y += __shfl_xor(acc.y, 32, 64);
  acc.z += __shfl_xor(acc.z, 32, 64);
  acc.w += __shfl_xor(acc.w, 32, 64);
  if (half == 0) {
    const float rdeg = 1.0f / fmaxf((float)(end - beg), 1.0f);
    const float one_eps = 1.0f + epsp[0];
    float4 ns = *(const float4*)(node + (size_t)wid * D + fo);
    float4 o;
    o.x = one_eps * ns.x + acc.x * rdeg;
    o.y = one_eps * ns.y + acc.y * rdeg;
    o.z = one_eps * ns.z + acc.z * rdeg;
    o.w = one_eps * ns.w + acc.w * rdeg;
    *(float4*)(A + (size_t)wid * D + fo) = o;
  }
}

// ---------------------------------------------------------------------------
// Tiled f32 GEMMs. TM=64, TN=64, TK=32, 256 threads, 4x4 micro-tile each.
// ---------------------------------------------------------------------------
#define TM 64
#define TN 64
#define TK 32
#define LDP 68

// GEMM1:  X1 = A @ W1 + b1     (A: [NN, D], X1: [NN, H])
__global__ __launch_bounds__(256) void gemm1_kernel(
    const float* __restrict__ A, const float* __restrict__ W1,
    const float* __restrict__ b1, float* __restrict__ X1) {
  __shared__ float As[TK][LDP];  // As[k][r]
  __shared__ float Bs[TK][LDP];  // Bs[k][c]
  const int tid = threadIdx.x;
  const int r0 = blockIdx.x * TM;
  const int c0 = blockIdx.y * TN;
  const int tx = tid & 15, ty = tid >> 4;
  float acc[4][4] = {};

  for (int k0 = 0; k0 < D; k0 += TK) {
#pragma unroll
    for (int l = 0; l < 2; ++l) {
      int e = tid + l * 256;      // 0..511
      int kg = e & 7;             // float4 group along k
      int r = e >> 3;             // 0..63
      int row = r0 + r;
      int rc = row < NN ? row : NN - 1;
      const float4 av = *(const float4*)(A + (size_t)rc * D + k0 + kg * 4);
      As[kg * 4 + 0][r] = av.x;
      As[kg * 4 + 1][r] = av.y;
      As[kg * 4 + 2][r] = av.z;
      As[kg * 4 + 3][r] = av.w;
    }
#pragma unroll
    for (int l = 0; l < 2; ++l) {
      int e = tid + l * 256;
      int cg = e & 15;            // float4 group along c
      int k = e >> 4;             // 0..31
      *(float4*)&Bs[k][cg * 4] =
          *(const float4*)(W1 + (size_t)(k0 + k) * H + c0 + cg * 4);
    }
    __syncthreads();
#pragma unroll
    for (int kk = 0; kk < TK; ++kk) {
      float4 av = *(const float4*)&As[kk][ty * 4];
      float4 bv = *(const float4*)&Bs[kk][tx * 4];
      float a[4] = {av.x, av.y, av.z, av.w};
      float b[4] = {bv.x, bv.y, bv.z, bv.w};
#pragma unroll
      for (int i = 0; i < 4; ++i)
#pragma unroll
        for (int j = 0; j < 4; ++j) acc[i][j] += a[i] * b[j];
    }
    __syncthreads();
  }
  float4 bias = *(const float4*)(b1 + c0 + tx * 4);
#pragma unroll
  for (int i = 0; i < 4; ++i) {
    int row = r0 + ty * 4 + i;
    if (row < NN) {
      float4 o;
      o.x = acc[i][0] + bias.x;
      o.y = acc[i][1] + bias.y;
      o.z = acc[i][2] + bias.z;
      o.w = acc[i][3] + bias.w;
      *(float4*)(X1 + (size_t)row * H + c0 + tx * 4) = o;
    }
  }
}

// GEMM2:  A[r][k] = relu(X1[r][k]*scale1[k] + shift1[k])   (K=H)
//         X2 = A @ W2 + b2     (X2: [NN, D])
__global__ __launch_bounds__(256) void gemm2_kernel(
    const float* __restrict__ X1, const float* __restrict__ norm1,
    const float* __restrict__ W2, const float* __restrict__ b2,
    float* __restrict__ X2) {
  __shared__ float As[TK][LDP];
  __shared__ float Bs[TK][LDP];
  const int tid = threadIdx.x;
  const int r0 = blockIdx.x * TM;
  const int c0 = blockIdx.y * TN;
  const int tx = tid & 15, ty = tid >> 4;
  float acc[4][4] = {};

  for (int k0 = 0; k0 < H; k0 += TK) {
#pragma unroll
    for (int l = 0; l < 2; ++l) {
      int e = tid + l * 256;
      int kg = e & 7;
      int r = e >> 3;
      int row = r0 + r;
      int rc = row < NN ? row : NN - 1;
      const float4 xv = *(const float4*)(X1 + (size_t)rc * H + k0 + kg * 4);
      const float4 sc = *(const float4*)(norm1 + k0 + kg * 4);
      const float4 sh = *(const float4*)(norm1 + H + k0 + kg * 4);
      As[kg * 4 + 0][r] = fmaxf(xv.x * sc.x + sh.x, 0.0f);
      As[kg * 4 + 1][r] = fmaxf(xv.y * sc.y + sh.y, 0.0f);
      As[kg * 4 + 2][r] = fmaxf(xv.z * sc.z + sh.z, 0.0f);
      As[kg * 4 + 3][r] = fmaxf(xv.w * sc.w + sh.w, 0.0f);
    }
#pragma unroll
    for (int l = 0; l < 2; ++l) {
      int e = tid + l * 256;
      int cg = e & 15;
      int k = e >> 4;
      *(float4*)&Bs[k][cg * 4] =
          *(const float4*)(W2 + (size_t)(k0 + k) * D + c0 + cg * 4);
    }
    __syncthreads();
#pragma unroll
    for (int kk = 0; kk < TK; ++kk) {
      float4 av = *(const float4*)&As[kk][ty * 4];
      float4 bv = *(const float4*)&Bs[kk][tx * 4];
      float a[4] = {av.x, av.y, av.z, av.w};
      float b[4] = {bv.x, bv.y, bv.z, bv.w};
#pragma unroll
      for (int i = 0; i < 4; ++i)
#pragma unroll
        for (int j = 0; j < 4; ++j) acc[i][j] += a[i] * b[j];
    }
    __syncthreads();
  }
  float4 bias = *(const float4*)(b2 + c0 + tx * 4);
#pragma unroll
  for (int i = 0; i < 4; ++i) {
    int row = r0 + ty * 4 + i;
    if (row < NN) {
      float4 o;
      o.x = acc[i][0] + bias.x;
      o.y = acc[i][1] + bias.y;
      o.z = acc[i][2] + bias.z;
      o.w = acc[i][3] + bias.w;
      *(float4*)(X2 + (size_t)row * D + c0 + tx * 4) = o;
    }
  }
}

// ---------------------------------------------------------------------------
// Column sum / sum-of-squares over NN rows (BatchNorm batch stats).
// grid=160: 160 atomic adds per column (vs 512 before) -> less per-address
// serialization at the L2 atomic unit.
// ---------------------------------------------------------------------------
template <int C>
__global__ __launch_bounds__(256) void colstats_kernel(
    const float* __restrict__ X, float* __restrict__ stats) {
  const int t = threadIdx.x;
  const int RPB = 256 / C;
  const int col = t % C;
  int r = blockIdx.x * RPB + t / C;
  const int stride = gridDim.x * RPB;
  float s = 0.0f, q = 0.0f;
  for (; r < NN; r += stride) {
    float v = X[(size_t)r * C + col];
    s += v;
    q += v * v;
  }
  atomicAdd(&stats[col], s);
  atomicAdd(&stats[C + col], q);
}

template <int C>
__global__ void finalize_norm_kernel(const float* __restrict__ stats,
                                     const float* __restrict__ gamma,
                                     const float* __restrict__ beta,
                                     float* __restrict__ norm) {
  int t = threadIdx.x;
  if (t < C) {
    const float inv_n = 1.0f / (float)NN;
    float mu = stats[t] * inv_n;
    float var = stats[C + t] * inv_n - mu * mu;
    float sc = gamma[t] * rsqrtf(var + BN_EPS);
    norm[t] = sc;
    norm[C + t] = beta[t] - mu * sc;
  }
}

// out = relu(X2 * scale2[c] + shift2[c])
__global__ __launch_bounds__(256) void final_kernel(
    const float* __restrict__ X2, const float* __restrict__ norm2,
    float* __restrict__ out) {
  int idx = blockIdx.x * blockDim.x + threadIdx.x;
  if (idx >= NN * D / 4) return;
  int c4 = (idx & (D / 4 - 1)) * 4;
  float4 v = *(const float4*)(X2 + (size_t)idx * 4);
  float4 sc = *(const float4*)(norm2 + c4);
  float4 sh = *(const float4*)(norm2 + D + c4);
  float4 o;
  o.x = fmaxf(v.x * sc.x + sh.x, 0.0f);
  o.y = fmaxf(v.y * sc.y + sh.y, 0.0f);
  o.z = fmaxf(v.z * sc.z + sh.z, 0.0f);
  o.w = fmaxf(v.w * sc.w + sh.w, 0.0f);
  *(float4*)(out + (size_t)idx * 4) = o;
}

extern "C" void kernel_launch(void* const* d_in, const int* in_sizes, int n_in,
                              void* d_out, int out_size, void* d_ws,
                              size_t ws_size, hipStream_t stream) {
  const float* node = (const float*)d_in[0];
  const float* edge = (const float*)d_in[1];
  const float* eps = (const float*)d_in[2];
  const float* W1 = (const float*)d_in[3];
  const float* b1 = (const float*)d_in[4];
  const float* g1 = (const float*)d_in[5];
  const float* be1 = (const float*)d_in[6];
  const float* W2 = (const float*)d_in[7];
  const float* b2 = (const float*)d_in[8];
  const float* g2 = (const float*)d_in[9];
  const float* be2 = (const float*)d_in[10];
  const int* src = (const int*)d_in[11];
  const int* dst = (const int*)d_in[12];
  float* ws = (float*)d_ws;
  int* wsi = (int*)d_ws;
  float* out = (float*)d_out;

  // zero: cnt, stats1, stats2
  hipMemsetAsync(ws, 0, (size_t)ZERO_ELEMS * sizeof(float), stream);

  hist_kernel<<<(NE + 255) / 256, 256, 0, stream>>>(dst, wsi + OFF_CNT);
  scan_kernel<<<1, 256, 0, stream>>>(wsi + OFF_CNT, wsi + OFF_RS,
                                     wsi + OFF_CUR);
  fill_kernel<<<(NE + 255) / 256, 256, 0, stream>>>(dst, wsi + OFF_CUR,
                                                    wsi + OFF_EID);
  gather_kernel<<<(NN * 64 + 255) / 256, 256, 0, stream>>>(
      node, edge, src, wsi + OFF_RS, wsi + OFF_EID, eps, ws + OFF_A);

  dim3 grid1((NN + TM - 1) / TM, H / TN);
  gemm1_kernel<<<grid1, 256, 0, stream>>>(ws + OFF_A, W1, b1, ws + OFF_X1);

  colstats_kernel<H><<<160, 256, 0, stream>>>(ws + OFF_X1, ws + OFF_STATS1);
  finalize_norm_kernel<H><<<1, H, 0, stream>>>(ws + OFF_STATS1, g1, be1,
                                               ws + OFF_NORM1);

  dim3 grid2((NN + TM - 1) / TM, D / TN);
  gemm2_kernel<<<grid2, 256, 0, stream>>>(ws + OFF_X1, ws + OFF_NORM1, W2, b2,
                                          ws + OFF_X2);

  colstats_kernel<D><<<160, 256, 0, stream>>>(ws + OFF_X2, ws + OFF_STATS2);
  finalize_norm_kernel<D><<<1, D, 0, stream>>>(ws + OFF_STATS2, g2, be2,
                                               ws + OFF_NORM2);

  final_kernel<<<(NN * D / 4 + 255) / 256, 256, 0, stream>>>(
      ws + OFF_X2, ws + OFF_NORM2, out);
}

// Round 4
// 636.526 us; speedup vs baseline: 2.4261x; 1.0351x over previous
//
#include <hip/hip_runtime.h>

#define NN 10000     // nodes
#define NE 640000    // edges
#define D  128
#define H  256       // 2*D hidden
#define BN_EPS 1e-5f

// ---- workspace layout (4-byte element offsets) ----
#define OFF_CNT    0                           // NN ints (zeroed)
#define OFF_STATS1 (NN)                        // 2H floats (zeroed)
#define OFF_STATS2 (NN + 2 * H)                // 2D floats (zeroed)
#define ZERO_ELEMS (NN + 2 * H + 2 * D)        // 10768
#define OFF_RS     ZERO_ELEMS                  // NN+1 ints
#define OFF_CUR    (OFF_RS + NN + 4)           // NN ints (padded to %4==0)
#define OFF_EID    (OFF_CUR + NN)              // NE ints
#define OFF_A      (OFF_EID + NE)              // NN*D floats (%4==0)
#define OFF_X1     (OFF_A + (size_t)NN * D)    // NN*H floats
#define OFF_X2     (OFF_X1 + (size_t)NN * H)   // NN*D floats
#define OFF_NORM1  (OFF_X2 + (size_t)NN * D)   // 2H floats
#define OFF_NORM2  (OFF_NORM1 + 2 * H)         // 2D floats

// ---------------------------------------------------------------------------
// CSR build: histogram -> exclusive scan -> fill edge-id buckets
// ---------------------------------------------------------------------------
__global__ __launch_bounds__(256) void hist_kernel(const int* __restrict__ dst,
                                                   int* __restrict__ cnt) {
  int e = blockIdx.x * blockDim.x + threadIdx.x;
  if (e < NE) atomicAdd(&cnt[dst[e]], 1);
}

// single block, 256 threads; each thread scans a 40-element chunk serially.
__global__ __launch_bounds__(256) void scan_kernel(const int* __restrict__ cnt,
                                                   int* __restrict__ rs,
                                                   int* __restrict__ cur) {
  __shared__ int part[256];
  __shared__ int tmp[256];
  const int t = threadIdx.x;
  const int CH = 40;  // 256*40 >= 10000
  int base = t * CH;
  int s = 0;
  for (int i = 0; i < CH; ++i) {
    int idx = base + i;
    if (idx < NN) s += cnt[idx];
  }
  part[t] = s;
  __syncthreads();
  int v = part[t];
  for (int off = 1; off < 256; off <<= 1) {
    tmp[t] = v;
    __syncthreads();
    if (t >= off) v += tmp[t - off];
    __syncthreads();
  }
  int excl = v - part[t];
  int run = excl;
  for (int i = 0; i < CH; ++i) {
    int idx = base + i;
    if (idx < NN) {
      rs[idx] = run;
      cur[idx] = run;
      run += cnt[idx];
    }
  }
  if (t == 0) rs[NN] = NE;
}

__global__ __launch_bounds__(256) void fill_kernel(const int* __restrict__ dst,
                                                   int* __restrict__ cur,
                                                   int* __restrict__ eid) {
  int e = blockIdx.x * blockDim.x + threadIdx.x;
  if (e < NE) {
    int pos = atomicAdd(&cur[dst[e]], 1);
    eid[pos] = e;
  }
}

// ---------------------------------------------------------------------------
// Gather v3: one 64-lane wave per destination node. Per 64-edge chunk, the
// wave batch-loads eid/src coalesced (ONE index-latency hit per chunk), then
// streams feature rows with indices served from registers via __shfl.
// Each 32-lane half covers one full 512B row per float4 load; halves process
// edges 2j / 2j+1, combined at the end with shfl_xor(32).
// A[d] = (1+eps)*node[d] + mean_e(node[src]+edge[e]).
// ---------------------------------------------------------------------------
__global__ __launch_bounds__(256) void gather_kernel(
    const float* __restrict__ node, const float* __restrict__ edge,
    const int* __restrict__ src, const int* __restrict__ rs,
    const int* __restrict__ eid, const float* __restrict__ epsp,
    float* __restrict__ A) {
  int wid = (blockIdx.x * 256 + (int)threadIdx.x) >> 6;
  if (wid >= NN) return;
  const int lane = threadIdx.x & 63;
  const int half = lane >> 5;
  const int fo = (lane & 31) * 4;
  const int beg = rs[wid];
  const int end = rs[wid + 1];
  float4 acc = {0.0f, 0.0f, 0.0f, 0.0f};

  for (int base = beg; base < end; base += 64) {
    const int n = min(64, end - base);
    // coalesced batch index load (clamped for tail lanes)
    int my_e = eid[base + (lane < n ? lane : n - 1)];
    int my_s = src[my_e];
    const int nPair = (n + 1) >> 1;
#pragma unroll 4
    for (int j = 0; j < nPair; ++j) {
      int idx = 2 * j + half;
      int sl = idx < n ? idx : n - 1;
      int e = __shfl(my_e, sl, 64);
      int s = __shfl(my_s, sl, 64);
      float w = idx < n ? 1.0f : 0.0f;
      float4 ev = *(const float4*)(edge + (size_t)e * D + fo);
      float4 nv = *(const float4*)(node + (size_t)s * D + fo);
      acc.x += w * (ev.x + nv.x);
      acc.y += w * (ev.y + nv.y);
      acc.z += w * (ev.z + nv.z);
      acc.w += w * (ev.w + nv.w);
    }
  }
  // combine the two halves (each holds a partial over the same columns)
  acc.x += __shfl_xor(acc.x, 32, 64);
  acc.y += __shfl_xor(acc.y, 32, 64);
  acc.z += __shfl_xor(acc.z, 32, 64);
  acc.w += __shfl_xor(acc.w, 32, 64);
  if (half == 0) {
    const float rdeg = 1.0f / fmaxf((float)(end - beg), 1.0f);
    const float one_eps = 1.0f + epsp[0];
    float4 ns = *(const float4*)(node + (size_t)wid * D + fo);
    float4 o;
    o.x = one_eps * ns.x + acc.x * rdeg;
    o.y = one_eps * ns.y + acc.y * rdeg;
    o.z = one_eps * ns.z + acc.z * rdeg;
    o.w = one_eps * ns.w + acc.w * rdeg;
    *(float4*)(A + (size_t)wid * D + fo) = o;
  }
}

// ---------------------------------------------------------------------------
// Tiled f32 GEMMs with fused BatchNorm column-stat accumulation.
// TM=64, TN=64, TK=32, 256 threads, 4x4 micro-tile each.
// Epilogue: per-thread col partials -> shfl butterfly over ty within wave ->
// LDS cross-wave combine -> one global atomicAdd per column per block.
// ---------------------------------------------------------------------------
#define TM 64
#define TN 64
#define TK 32
#define LDP 68

// GEMM1:  X1 = A @ W1 + b1  (A: [NN,D], X1: [NN,H]); stats1 += colsum/colsq
__global__ __launch_bounds__(256) void gemm1_kernel(
    const float* __restrict__ A, const float* __restrict__ W1,
    const float* __restrict__ b1, float* __restrict__ X1,
    float* __restrict__ stats) {
  __shared__ float As[TK][LDP];
  __shared__ float Bs[TK][LDP];
  __shared__ float cs[4][64];
  __shared__ float cq[4][64];
  const int tid = threadIdx.x;
  const int r0 = blockIdx.x * TM;
  const int c0 = blockIdx.y * TN;
  const int tx = tid & 15, ty = tid >> 4;
  float acc[4][4] = {};

  for (int k0 = 0; k0 < D; k0 += TK) {
#pragma unroll
    for (int l = 0; l < 2; ++l) {
      int e = tid + l * 256;
      int kg = e & 7;
      int r = e >> 3;
      int row = r0 + r;
      int rc = row < NN ? row : NN - 1;
      const float4 av = *(const float4*)(A + (size_t)rc * D + k0 + kg * 4);
      As[kg * 4 + 0][r] = av.x;
      As[kg * 4 + 1][r] = av.y;
      As[kg * 4 + 2][r] = av.z;
      As[kg * 4 + 3][r] = av.w;
    }
#pragma unroll
    for (int l = 0; l < 2; ++l) {
      int e = tid + l * 256;
      int cg = e & 15;
      int k = e >> 4;
      *(float4*)&Bs[k][cg * 4] =
          *(const float4*)(W1 + (size_t)(k0 + k) * H + c0 + cg * 4);
    }
    __syncthreads();
#pragma unroll
    for (int kk = 0; kk < TK; ++kk) {
      float4 av = *(const float4*)&As[kk][ty * 4];
      float4 bv = *(const float4*)&Bs[kk][tx * 4];
      float a[4] = {av.x, av.y, av.z, av.w};
      float b[4] = {bv.x, bv.y, bv.z, bv.w};
#pragma unroll
      for (int i = 0; i < 4; ++i)
#pragma unroll
        for (int j = 0; j < 4; ++j) acc[i][j] += a[i] * b[j];
    }
    __syncthreads();
  }
  float4 bias = *(const float4*)(b1 + c0 + tx * 4);
  float s[4] = {}, q[4] = {};
#pragma unroll
  for (int i = 0; i < 4; ++i) {
    int row = r0 + ty * 4 + i;
    if (row < NN) {
      float o[4];
      o[0] = acc[i][0] + bias.x;
      o[1] = acc[i][1] + bias.y;
      o[2] = acc[i][2] + bias.z;
      o[3] = acc[i][3] + bias.w;
#pragma unroll
      for (int j = 0; j < 4; ++j) {
        s[j] += o[j];
        q[j] += o[j] * o[j];
      }
      float4 ov = {o[0], o[1], o[2], o[3]};
      *(float4*)(X1 + (size_t)row * H + c0 + tx * 4) = ov;
    }
  }
  const int lane = tid & 63;
  const int wv = tid >> 6;
#pragma unroll
  for (int j = 0; j < 4; ++j) {
    float sv = s[j], qv = q[j];
    sv += __shfl_xor(sv, 16, 64);
    qv += __shfl_xor(qv, 16, 64);
    sv += __shfl_xor(sv, 32, 64);
    qv += __shfl_xor(qv, 32, 64);
    if (lane < 16) {
      cs[wv][lane * 4 + j] = sv;
      cq[wv][lane * 4 + j] = qv;
    }
  }
  __syncthreads();
  if (tid < 64) {
    float sv = cs[0][tid] + cs[1][tid] + cs[2][tid] + cs[3][tid];
    float qv = cq[0][tid] + cq[1][tid] + cq[2][tid] + cq[3][tid];
    atomicAdd(&stats[c0 + tid], sv);
    atomicAdd(&stats[H + c0 + tid], qv);
  }
}

// GEMM2:  Ain[r][k] = relu(X1[r][k]*scale1[k]+shift1[k]); X2 = Ain@W2 + b2
//         stats2 += colsum/colsq of X2
__global__ __launch_bounds__(256) void gemm2_kernel(
    const float* __restrict__ X1, const float* __restrict__ norm1,
    const float* __restrict__ W2, const float* __restrict__ b2,
    float* __restrict__ X2, float* __restrict__ stats) {
  __shared__ float As[TK][LDP];
  __shared__ float Bs[TK][LDP];
  __shared__ float cs[4][64];
  __shared__ float cq[4][64];
  const int tid = threadIdx.x;
  const int r0 = blockIdx.x * TM;
  const int c0 = blockIdx.y * TN;
  const int tx = tid & 15, ty = tid >> 4;
  float acc[4][4] = {};

  for (int k0 = 0; k0 < H; k0 += TK) {
#pragma unroll
    for (int l = 0; l < 2; ++l) {
      int e = tid + l * 256;
      int kg = e & 7;
      int r = e >> 3;
      int row = r0 + r;
      int rc = row < NN ? row : NN - 1;
      const float4 xv = *(const float4*)(X1 + (size_t)rc * H + k0 + kg * 4);
      const float4 sc = *(const float4*)(norm1 + k0 + kg * 4);
      const float4 sh = *(const float4*)(norm1 + H + k0 + kg * 4);
      As[kg * 4 + 0][r] = fmaxf(xv.x * sc.x + sh.x, 0.0f);
      As[kg * 4 + 1][r] = fmaxf(xv.y * sc.y + sh.y, 0.0f);
      As[kg * 4 + 2][r] = fmaxf(xv.z * sc.z + sh.z, 0.0f);
      As[kg * 4 + 3][r] = fmaxf(xv.w * sc.w + sh.w, 0.0f);
    }
#pragma unroll
    for (int l = 0; l < 2; ++l) {
      int e = tid + l * 256;
      int cg = e & 15;
      int k = e >> 4;
      *(float4*)&Bs[k][cg * 4] =
          *(const float4*)(W2 + (size_t)(k0 + k) * D + c0 + cg * 4);
    }
    __syncthreads();
#pragma unroll
    for (int kk = 0; kk < TK; ++kk) {
      float4 av = *(const float4*)&As[kk][ty * 4];
      float4 bv = *(const float4*)&Bs[kk][tx * 4];
      float a[4] = {av.x, av.y, av.z, av.w};
      float b[4] = {bv.x, bv.y, bv.z, bv.w};
#pragma unroll
      for (int i = 0; i < 4; ++i)
#pragma unroll
        for (int j = 0; j < 4; ++j) acc[i][j] += a[i] * b[j];
    }
    __syncthreads();
  }
  float4 bias = *(const float4*)(b2 + c0 + tx * 4);
  float s[4] = {}, q[4] = {};
#pragma unroll
  for (int i = 0; i < 4; ++i) {
    int row = r0 + ty * 4 + i;
    if (row < NN) {
      float o[4];
      o[0] = acc[i][0] + bias.x;
      o[1] = acc[i][1] + bias.y;
      o[2] = acc[i][2] + bias.z;
      o[3] = acc[i][3] + bias.w;
#pragma unroll
      for (int j = 0; j < 4; ++j) {
        s[j] += o[j];
        q[j] += o[j] * o[j];
      }
      float4 ov = {o[0], o[1], o[2], o[3]};
      *(float4*)(X2 + (size_t)row * D + c0 + tx * 4) = ov;
    }
  }
  const int lane = tid & 63;
  const int wv = tid >> 6;
#pragma unroll
  for (int j = 0; j < 4; ++j) {
    float sv = s[j], qv = q[j];
    sv += __shfl_xor(sv, 16, 64);
    qv += __shfl_xor(qv, 16, 64);
    sv += __shfl_xor(sv, 32, 64);
    qv += __shfl_xor(qv, 32, 64);
    if (lane < 16) {
      cs[wv][lane * 4 + j] = sv;
      cq[wv][lane * 4 + j] = qv;
    }
  }
  __syncthreads();
  if (tid < 64) {
    float sv = cs[0][tid] + cs[1][tid] + cs[2][tid] + cs[3][tid];
    float qv = cq[0][tid] + cq[1][tid] + cq[2][tid] + cq[3][tid];
    atomicAdd(&stats[c0 + tid], sv);
    atomicAdd(&stats[D + c0 + tid], qv);
  }
}

template <int C>
__global__ void finalize_norm_kernel(const float* __restrict__ stats,
                                     const float* __restrict__ gamma,
                                     const float* __restrict__ beta,
                                     float* __restrict__ norm) {
  int t = threadIdx.x;
  if (t < C) {
    const float inv_n = 1.0f / (float)NN;
    float mu = stats[t] * inv_n;
    float var = stats[C + t] * inv_n - mu * mu;
    float sc = gamma[t] * rsqrtf(var + BN_EPS);
    norm[t] = sc;
    norm[C + t] = beta[t] - mu * sc;
  }
}

// out = relu(X2 * scale2[c] + shift2[c])
__global__ __launch_bounds__(256) void final_kernel(
    const float* __restrict__ X2, const float* __restrict__ norm2,
    float* __restrict__ out) {
  int idx = blockIdx.x * blockDim.x + threadIdx.x;
  if (idx >= NN * D / 4) return;
  int c4 = (idx & (D / 4 - 1)) * 4;
  float4 v = *(const float4*)(X2 + (size_t)idx * 4);
  float4 sc = *(const float4*)(norm2 + c4);
  float4 sh = *(const float4*)(norm2 + D + c4);
  float4 o;
  o.x = fmaxf(v.x * sc.x + sh.x, 0.0f);
  o.y = fmaxf(v.y * sc.y + sh.y, 0.0f);
  o.z = fmaxf(v.z * sc.z + sh.z, 0.0f);
  o.w = fmaxf(v.w * sc.w + sh.w, 0.0f);
  *(float4*)(out + (size_t)idx * 4) = o;
}

extern "C" void kernel_launch(void* const* d_in, const int* in_sizes, int n_in,
                              void* d_out, int out_size, void* d_ws,
                              size_t ws_size, hipStream_t stream) {
  const float* node = (const float*)d_in[0];
  const float* edge = (const float*)d_in[1];
  const float* eps = (const float*)d_in[2];
  const float* W1 = (const float*)d_in[3];
  const float* b1 = (const float*)d_in[4];
  const float* g1 = (const float*)d_in[5];
  const float* be1 = (const float*)d_in[6];
  const float* W2 = (const float*)d_in[7];
  const float* b2 = (const float*)d_in[8];
  const float* g2 = (const float*)d_in[9];
  const float* be2 = (const float*)d_in[10];
  const int* src = (const int*)d_in[11];
  const int* dst = (const int*)d_in[12];
  float* ws = (float*)d_ws;
  int* wsi = (int*)d_ws;
  float* out = (float*)d_out;

  // zero: cnt, stats1, stats2
  hipMemsetAsync(ws, 0, (size_t)ZERO_ELEMS * sizeof(float), stream);

  hist_kernel<<<(NE + 255) / 256, 256, 0, stream>>>(dst, wsi + OFF_CNT);
  scan_kernel<<<1, 256, 0, stream>>>(wsi + OFF_CNT, wsi + OFF_RS,
                                     wsi + OFF_CUR);
  fill_kernel<<<(NE + 255) / 256, 256, 0, stream>>>(dst, wsi + OFF_CUR,
                                                    wsi + OFF_EID);
  gather_kernel<<<(NN * 64 + 255) / 256, 256, 0, stream>>>(
      node, edge, src, wsi + OFF_RS, wsi + OFF_EID, eps, ws + OFF_A);

  dim3 grid1((NN + TM - 1) / TM, H / TN);
  gemm1_kernel<<<grid1, 256, 0, stream>>>(ws + OFF_A, W1, b1, ws + OFF_X1,
                                          ws + OFF_STATS1);
  finalize_norm_kernel<H><<<1, H, 0, stream>>>(ws + OFF_STATS1, g1, be1,
                                               ws + OFF_NORM1);

  dim3 grid2((NN + TM - 1) / TM, D / TN);
  gemm2_kernel<<<grid2, 256, 0, stream>>>(ws + OFF_X1, ws + OFF_NORM1, W2, b2,
                                          ws + OFF_X2, ws + OFF_STATS2);
  finalize_norm_kernel<D><<<1, D, 0, stream>>>(ws + OFF_STATS2, g2, be2,
                                               ws + OFF_NORM2);

  final_kernel<<<(NN * D / 4 + 255) / 256, 256, 0, stream>>>(
      ws + OFF_X2, ws + OFF_NORM2, out);
}

// Round 6
// 614.536 us; speedup vs baseline: 2.5129x; 1.0358x over previous
//
#include <hip/hip_runtime.h>

#define NN 10000     // nodes
#define NE 640000    // edges
#define D  128
#define H  256       // 2*D hidden
#define BN_EPS 1e-5f

// ---- workspace layout (4-byte element offsets) ----
#define OFF_CNT    0                           // NN ints (zeroed)
#define OFF_STATS1 (NN)                        // 2H floats (zeroed)
#define OFF_STATS2 (NN + 2 * H)                // 2D floats (zeroed)
#define ZERO_ELEMS (NN + 2 * H + 2 * D)        // 10768
#define OFF_RS     ZERO_ELEMS                  // NN+1 ints
#define OFF_CUR    (OFF_RS + NN + 4)           // NN ints (padded to %4==0)
#define OFF_EID    (OFF_CUR + NN)              // NE ints
#define OFF_A      (OFF_EID + NE)              // NN*D floats (%4==0)
#define OFF_X1     (OFF_A + (size_t)NN * D)    // NN*H floats
#define OFF_X2     (OFF_X1 + (size_t)NN * H)   // NN*D floats

// native clang vector type: __builtin_nontemporal_* accepts these (it rejects
// HIP_vector_type wrappers like float4)
typedef float vfloat4 __attribute__((ext_vector_type(4)));

__device__ inline float4 ntload4(const float* p) {
  vfloat4 v = __builtin_nontemporal_load((const vfloat4*)p);
  return make_float4(v.x, v.y, v.z, v.w);
}
__device__ inline void ntstore4(float* p, float4 o) {
  vfloat4 v = {o.x, o.y, o.z, o.w};
  __builtin_nontemporal_store(v, (vfloat4*)p);
}

// ---------------------------------------------------------------------------
// CSR build: histogram -> exclusive scan -> fill edge-id buckets
// ---------------------------------------------------------------------------
__global__ __launch_bounds__(256) void hist_kernel(const int* __restrict__ dst,
                                                   int* __restrict__ cnt) {
  int e = blockIdx.x * blockDim.x + threadIdx.x;
  if (e < NE) atomicAdd(&cnt[dst[e]], 1);
}

// single block, 256 threads; each thread scans a 40-element chunk serially.
__global__ __launch_bounds__(256) void scan_kernel(const int* __restrict__ cnt,
                                                   int* __restrict__ rs,
                                                   int* __restrict__ cur) {
  __shared__ int part[256];
  __shared__ int tmp[256];
  const int t = threadIdx.x;
  const int CH = 40;  // 256*40 >= 10000
  int base = t * CH;
  int s = 0;
  for (int i = 0; i < CH; ++i) {
    int idx = base + i;
    if (idx < NN) s += cnt[idx];
  }
  part[t] = s;
  __syncthreads();
  int v = part[t];
  for (int off = 1; off < 256; off <<= 1) {
    tmp[t] = v;
    __syncthreads();
    if (t >= off) v += tmp[t - off];
    __syncthreads();
  }
  int excl = v - part[t];
  int run = excl;
  for (int i = 0; i < CH; ++i) {
    int idx = base + i;
    if (idx < NN) {
      rs[idx] = run;
      cur[idx] = run;
      run += cnt[idx];
    }
  }
  if (t == 0) rs[NN] = NE;
}

__global__ __launch_bounds__(256) void fill_kernel(const int* __restrict__ dst,
                                                   int* __restrict__ cur,
                                                   int* __restrict__ eid) {
  int e = blockIdx.x * blockDim.x + threadIdx.x;
  if (e < NE) {
    int pos = atomicAdd(&cur[dst[e]], 1);
    eid[pos] = e;
  }
}

// ---------------------------------------------------------------------------
// Gather: one 64-lane wave per destination node. Per 64-edge chunk the wave
// batch-loads eid/src coalesced, then streams feature rows with indices from
// registers via __shfl. Each 32-lane half covers one 512B row per float4
// load; halves process edges 2j/2j+1, combined at the end with shfl_xor(32).
// Edge rows are loaded NON-TEMPORAL (read-once stream -> don't evict the hot
// node rows). A[d] = (1+eps)*node[d] + mean_e(node[src]+edge[e]).
// ---------------------------------------------------------------------------
__global__ __launch_bounds__(256) void gather_kernel(
    const float* __restrict__ node, const float* __restrict__ edge,
    const int* __restrict__ src, const int* __restrict__ rs,
    const int* __restrict__ eid, const float* __restrict__ epsp,
    float* __restrict__ A) {
  int wid = (blockIdx.x * 256 + (int)threadIdx.x) >> 6;
  if (wid >= NN) return;
  const int lane = threadIdx.x & 63;
  const int half = lane >> 5;
  const int fo = (lane & 31) * 4;
  const int beg = rs[wid];
  const int end = rs[wid + 1];
  float4 acc = {0.0f, 0.0f, 0.0f, 0.0f};

  for (int base = beg; base < end; base += 64) {
    const int n = min(64, end - base);
    int my_e = eid[base + (lane < n ? lane : n - 1)];
    int my_s = src[my_e];
    const int nPair = (n + 1) >> 1;
#pragma unroll 8
    for (int j = 0; j < nPair; ++j) {
      int idx = 2 * j + half;
      int sl = idx < n ? idx : n - 1;
      int e = __shfl(my_e, sl, 64);
      int s = __shfl(my_s, sl, 64);
      float w = idx < n ? 1.0f : 0.0f;
      float4 ev = ntload4(edge + (size_t)e * D + fo);
      float4 nv = *(const float4*)(node + (size_t)s * D + fo);
      acc.x += w * (ev.x + nv.x);
      acc.y += w * (ev.y + nv.y);
      acc.z += w * (ev.z + nv.z);
      acc.w += w * (ev.w + nv.w);
    }
  }
  acc.x += __shfl_xor(acc.x, 32, 64);
  acc.y += __shfl_xor(acc.y, 32, 64);
  acc.z += __shfl_xor(acc.z, 32, 64);
  acc.w += __shfl_xor(acc.w, 32, 64);
  if (half == 0) {
    const float rdeg = 1.0f / fmaxf((float)(end - beg), 1.0f);
    const float one_eps = 1.0f + epsp[0];
    float4 ns = *(const float4*)(node + (size_t)wid * D + fo);
    float4 o;
    o.x = one_eps * ns.x + acc.x * rdeg;
    o.y = one_eps * ns.y + acc.y * rdeg;
    o.z = one_eps * ns.z + acc.z * rdeg;
    o.w = one_eps * ns.w + acc.w * rdeg;
    *(float4*)(A + (size_t)wid * D + fo) = o;
  }
}

// ---------------------------------------------------------------------------
// Tiled f32 GEMMs with fused BatchNorm column-stat accumulation.
// TM=64, TN=64, TK=32, 256 threads, 4x4 micro-tile each.
// ---------------------------------------------------------------------------
#define TM 64
#define TN 64
#define TK 32
#define LDP 68

// GEMM1:  X1 = A @ W1 + b1  (A: [NN,D], X1: [NN,H]); stats1 += colsum/colsq
__global__ __launch_bounds__(256) void gemm1_kernel(
    const float* __restrict__ A, const float* __restrict__ W1,
    const float* __restrict__ b1, float* __restrict__ X1,
    float* __restrict__ stats) {
  __shared__ float As[TK][LDP];
  __shared__ float Bs[TK][LDP];
  __shared__ float cs[4][64];
  __shared__ float cq[4][64];
  const int tid = threadIdx.x;
  const int r0 = blockIdx.x * TM;
  const int c0 = blockIdx.y * TN;
  const int tx = tid & 15, ty = tid >> 4;
  float acc[4][4] = {};

  for (int k0 = 0; k0 < D; k0 += TK) {
#pragma unroll
    for (int l = 0; l < 2; ++l) {
      int e = tid + l * 256;
      int kg = e & 7;
      int r = e >> 3;
      int row = r0 + r;
      int rc = row < NN ? row : NN - 1;
      const float4 av = *(const float4*)(A + (size_t)rc * D + k0 + kg * 4);
      As[kg * 4 + 0][r] = av.x;
      As[kg * 4 + 1][r] = av.y;
      As[kg * 4 + 2][r] = av.z;
      As[kg * 4 + 3][r] = av.w;
    }
#pragma unroll
    for (int l = 0; l < 2; ++l) {
      int e = tid + l * 256;
      int cg = e & 15;
      int k = e >> 4;
      *(float4*)&Bs[k][cg * 4] =
          *(const float4*)(W1 + (size_t)(k0 + k) * H + c0 + cg * 4);
    }
    __syncthreads();
#pragma unroll
    for (int kk = 0; kk < TK; ++kk) {
      float4 av = *(const float4*)&As[kk][ty * 4];
      float4 bv = *(const float4*)&Bs[kk][tx * 4];
      float a[4] = {av.x, av.y, av.z, av.w};
      float b[4] = {bv.x, bv.y, bv.z, bv.w};
#pragma unroll
      for (int i = 0; i < 4; ++i)
#pragma unroll
        for (int j = 0; j < 4; ++j) acc[i][j] += a[i] * b[j];
    }
    __syncthreads();
  }
  float4 bias = *(const float4*)(b1 + c0 + tx * 4);
  float s[4] = {}, q[4] = {};
#pragma unroll
  for (int i = 0; i < 4; ++i) {
    int row = r0 + ty * 4 + i;
    if (row < NN) {
      float o[4];
      o[0] = acc[i][0] + bias.x;
      o[1] = acc[i][1] + bias.y;
      o[2] = acc[i][2] + bias.z;
      o[3] = acc[i][3] + bias.w;
#pragma unroll
      for (int j = 0; j < 4; ++j) {
        s[j] += o[j];
        q[j] += o[j] * o[j];
      }
      float4 ov = {o[0], o[1], o[2], o[3]};
      *(float4*)(X1 + (size_t)row * H + c0 + tx * 4) = ov;
    }
  }
  const int lane = tid & 63;
  const int wv = tid >> 6;
#pragma unroll
  for (int j = 0; j < 4; ++j) {
    float sv = s[j], qv = q[j];
    sv += __shfl_xor(sv, 16, 64);
    qv += __shfl_xor(qv, 16, 64);
    sv += __shfl_xor(sv, 32, 64);
    qv += __shfl_xor(qv, 32, 64);
    if (lane < 16) {
      cs[wv][lane * 4 + j] = sv;
      cq[wv][lane * 4 + j] = qv;
    }
  }
  __syncthreads();
  if (tid < 64) {
    float sv = cs[0][tid] + cs[1][tid] + cs[2][tid] + cs[3][tid];
    float qv = cq[0][tid] + cq[1][tid] + cq[2][tid] + cq[3][tid];
    atomicAdd(&stats[c0 + tid], sv);
    atomicAdd(&stats[H + c0 + tid], qv);
  }
}

// GEMM2: per-block BN1 finalize (stats1 -> scale/shift in LDS), then
//        Ain[r][k] = relu(X1[r][k]*sc[k]+sh[k]); X2 = Ain@W2 + b2;
//        stats2 += colsum/colsq of X2
__global__ __launch_bounds__(256) void gemm2_kernel(
    const float* __restrict__ X1, const float* __restrict__ stats1,
    const float* __restrict__ gamma1, const float* __restrict__ beta1,
    const float* __restrict__ W2, const float* __restrict__ b2,
    float* __restrict__ X2, float* __restrict__ stats) {
  __shared__ float As[TK][LDP];
  __shared__ float Bs[TK][LDP];
  __shared__ float cs[4][64];
  __shared__ float cq[4][64];
  __shared__ float nsc[H];
  __shared__ float nsh[H];
  const int tid = threadIdx.x;
  const int r0 = blockIdx.x * TM;
  const int c0 = blockIdx.y * TN;
  const int tx = tid & 15, ty = tid >> 4;
  float acc[4][4] = {};

  {  // BN1 finalize: tid == column (H == 256 == blockDim)
    const float inv_n = 1.0f / (float)NN;
    float mu = stats1[tid] * inv_n;
    float var = stats1[H + tid] * inv_n - mu * mu;
    float sc = gamma1[tid] * rsqrtf(var + BN_EPS);
    nsc[tid] = sc;
    nsh[tid] = beta1[tid] - mu * sc;
  }
  __syncthreads();

  for (int k0 = 0; k0 < H; k0 += TK) {
#pragma unroll
    for (int l = 0; l < 2; ++l) {
      int e = tid + l * 256;
      int kg = e & 7;
      int r = e >> 3;
      int row = r0 + r;
      int rc = row < NN ? row : NN - 1;
      const float4 xv = *(const float4*)(X1 + (size_t)rc * H + k0 + kg * 4);
      const float4 sc = *(const float4*)&nsc[k0 + kg * 4];
      const float4 sh = *(const float4*)&nsh[k0 + kg * 4];
      As[kg * 4 + 0][r] = fmaxf(xv.x * sc.x + sh.x, 0.0f);
      As[kg * 4 + 1][r] = fmaxf(xv.y * sc.y + sh.y, 0.0f);
      As[kg * 4 + 2][r] = fmaxf(xv.z * sc.z + sh.z, 0.0f);
      As[kg * 4 + 3][r] = fmaxf(xv.w * sc.w + sh.w, 0.0f);
    }
#pragma unroll
    for (int l = 0; l < 2; ++l) {
      int e = tid + l * 256;
      int cg = e & 15;
      int k = e >> 4;
      *(float4*)&Bs[k][cg * 4] =
          *(const float4*)(W2 + (size_t)(k0 + k) * D + c0 + cg * 4);
    }
    __syncthreads();
#pragma unroll
    for (int kk = 0; kk < TK; ++kk) {
      float4 av = *(const float4*)&As[kk][ty * 4];
      float4 bv = *(const float4*)&Bs[kk][tx * 4];
      float a[4] = {av.x, av.y, av.z, av.w};
      float b[4] = {bv.x, bv.y, bv.z, bv.w};
#pragma unroll
      for (int i = 0; i < 4; ++i)
#pragma unroll
        for (int j = 0; j < 4; ++j) acc[i][j] += a[i] * b[j];
    }
    __syncthreads();
  }
  float4 bias = *(const float4*)(b2 + c0 + tx * 4);
  float s[4] = {}, q[4] = {};
#pragma unroll
  for (int i = 0; i < 4; ++i) {
    int row = r0 + ty * 4 + i;
    if (row < NN) {
      float o[4];
      o[0] = acc[i][0] + bias.x;
      o[1] = acc[i][1] + bias.y;
      o[2] = acc[i][2] + bias.z;
      o[3] = acc[i][3] + bias.w;
#pragma unroll
      for (int j = 0; j < 4; ++j) {
        s[j] += o[j];
        q[j] += o[j] * o[j];
      }
      float4 ov = {o[0], o[1], o[2], o[3]};
      *(float4*)(X2 + (size_t)row * D + c0 + tx * 4) = ov;
    }
  }
  const int lane = tid & 63;
  const int wv = tid >> 6;
#pragma unroll
  for (int j = 0; j < 4; ++j) {
    float sv = s[j], qv = q[j];
    sv += __shfl_xor(sv, 16, 64);
    qv += __shfl_xor(qv, 16, 64);
    sv += __shfl_xor(sv, 32, 64);
    qv += __shfl_xor(qv, 32, 64);
    if (lane < 16) {
      cs[wv][lane * 4 + j] = sv;
      cq[wv][lane * 4 + j] = qv;
    }
  }
  __syncthreads();
  if (tid < 64) {
    float sv = cs[0][tid] + cs[1][tid] + cs[2][tid] + cs[3][tid];
    float qv = cq[0][tid] + cq[1][tid] + cq[2][tid] + cq[3][tid];
    atomicAdd(&stats[c0 + tid], sv);
    atomicAdd(&stats[D + c0 + tid], qv);
  }
}

// final: per-block BN2 finalize, then out = relu(X2*sc[c]+sh[c]) (NT store)
__global__ __launch_bounds__(256) void final_kernel(
    const float* __restrict__ X2, const float* __restrict__ stats2,
    const float* __restrict__ gamma2, const float* __restrict__ beta2,
    float* __restrict__ out) {
  __shared__ float nsc[D];
  __shared__ float nsh[D];
  const int t = threadIdx.x;
  if (t < D) {
    const float inv_n = 1.0f / (float)NN;
    float mu = stats2[t] * inv_n;
    float var = stats2[D + t] * inv_n - mu * mu;
    float sc = gamma2[t] * rsqrtf(var + BN_EPS);
    nsc[t] = sc;
    nsh[t] = beta2[t] - mu * sc;
  }
  __syncthreads();
  int idx = blockIdx.x * blockDim.x + t;
  if (idx >= NN * D / 4) return;
  int c4 = (idx & (D / 4 - 1)) * 4;
  float4 v = *(const float4*)(X2 + (size_t)idx * 4);
  float4 sc = *(const float4*)&nsc[c4];
  float4 sh = *(const float4*)&nsh[c4];
  float4 o;
  o.x = fmaxf(v.x * sc.x + sh.x, 0.0f);
  o.y = fmaxf(v.y * sc.y + sh.y, 0.0f);
  o.z = fmaxf(v.z * sc.z + sh.z, 0.0f);
  o.w = fmaxf(v.w * sc.w + sh.w, 0.0f);
  ntstore4(out + (size_t)idx * 4, o);
}

extern "C" void kernel_launch(void* const* d_in, const int* in_sizes, int n_in,
                              void* d_out, int out_size, void* d_ws,
                              size_t ws_size, hipStream_t stream) {
  const float* node = (const float*)d_in[0];
  const float* edge = (const float*)d_in[1];
  const float* eps = (const float*)d_in[2];
  const float* W1 = (const float*)d_in[3];
  const float* b1 = (const float*)d_in[4];
  const float* g1 = (const float*)d_in[5];
  const float* be1 = (const float*)d_in[6];
  const float* W2 = (const float*)d_in[7];
  const float* b2 = (const float*)d_in[8];
  const float* g2 = (const float*)d_in[9];
  const float* be2 = (const float*)d_in[10];
  const int* src = (const int*)d_in[11];
  const int* dst = (const int*)d_in[12];
  float* ws = (float*)d_ws;
  int* wsi = (int*)d_ws;
  float* out = (float*)d_out;

  // zero: cnt, stats1, stats2
  (void)hipMemsetAsync(ws, 0, (size_t)ZERO_ELEMS * sizeof(float), stream);

  hist_kernel<<<(NE + 255) / 256, 256, 0, stream>>>(dst, wsi + OFF_CNT);
  scan_kernel<<<1, 256, 0, stream>>>(wsi + OFF_CNT, wsi + OFF_RS,
                                     wsi + OFF_CUR);
  fill_kernel<<<(NE + 255) / 256, 256, 0, stream>>>(dst, wsi + OFF_CUR,
                                                    wsi + OFF_EID);
  gather_kernel<<<(NN * 64 + 255) / 256, 256, 0, stream>>>(
      node, edge, src, wsi + OFF_RS, wsi + OFF_EID, eps, ws + OFF_A);

  dim3 grid1((NN + TM - 1) / TM, H / TN);
  gemm1_kernel<<<grid1, 256, 0, stream>>>(ws + OFF_A, W1, b1, ws + OFF_X1,
                                          ws + OFF_STATS1);

  dim3 grid2((NN + TM - 1) / TM, D / TN);
  gemm2_kernel<<<grid2, 256, 0, stream>>>(ws + OFF_X1, ws + OFF_STATS1, g1,
                                          be1, W2, b2, ws + OFF_X2,
                                          ws + OFF_STATS2);

  final_kernel<<<(NN * D / 4 + 255) / 256, 256, 0, stream>>>(
      ws + OFF_X2, ws + OFF_STATS2, g2, be2, out);
}